// Round 15
// baseline (33.774 us; speedup 1.0000x reference)
//
#include <hip/hip_runtime.h>

#define MT 64     // number of event types M
#define KK 4      // number of kernels K
#define NBK 4096  // scan blocks (512 WGs x 8 waves)
#define MAXB 49   // events/block per LDS chunk (N <= 200704 in one chunk; larger N loops)

// ---------- helpers ----------
__device__ __forceinline__ float wredf(float v) {
  #pragma unroll
  for (int off = 32; off > 0; off >>= 1) v += __shfl_xor(v, off, 64);
  return v;
}
__device__ __forceinline__ float4 f4fma(float4 a, float4 b, float4 c) { // a*b+c
  return make_float4(fmaf(a.x,b.x,c.x), fmaf(a.y,b.y,c.y),
                     fmaf(a.z,b.z,c.z), fmaf(a.w,b.w,c.w));
}
__device__ __forceinline__ float4 f4mul(float4 a, float4 b) {
  return make_float4(a.x*b.x, a.y*b.y, a.z*b.z, a.w*b.w);
}
__device__ __forceinline__ float parse_T(const int* Tp) {
  int v = *Tp;
  if (v >= 1 && v <= 1000000000) return (float)v;
  return __int_as_float(v);
}

// ---------- K1: single serial pass (R14-proven) + out[0] zeroing ----------
__global__ __launch_bounds__(512, 4) void k_phase1(
    const float* __restrict__ t, const int* __restrict__ mi,
    const float* __restrict__ alpha, const float* __restrict__ gamma,
    const int* __restrict__ Tp,
    float* __restrict__ slG,
    float4* __restrict__ Cl8, float4* __restrict__ Dc8,
    float4* __restrict__ Ag, float4* __restrict__ gdec,
    float* __restrict__ compP, float* __restrict__ out, int N, int B)
{
  __shared__ float4 AT4[MT*MT];                       // 64 KB
  __shared__ __align__(16) unsigned char pool[8320];  // d4t+miL (serial) / cw+cwd (scan)
  __shared__ float sL[8*MAXB];                        // per-event local intensity
  __shared__ float4 asumS[MT];
  __shared__ float red[8];
  float4*        d4t = (float4*)pool;                 // [8*MAXB]
  unsigned char* miL = pool + 8*MAXB*16;              // [8*MAXB]
  float4*        cw  = (float4*)pool;                 // [512] post-serial overlay
  float4*        cwd = (float4*)(pool + 8192);        // [8]

  const int tid = threadIdx.x, lane = tid & 63, wv = tid >> 6;
  const float g0=gamma[0], g1=gamma[1], g2=gamma[2], g3=gamma[3];

  if (blockIdx.x == 0 && tid == 0) out[0] = 0.f;      // race-free: k_lam is a later node

  #pragma unroll
  for (int idx = tid; idx < MT*MT; idx += 512) {
    float a0=alpha[idx],         a1=alpha[MT*MT+idx];
    float a2=alpha[2*MT*MT+idx], a3=alpha[3*MT*MT+idx];
    AT4[idx] = make_float4(g0*a0, g1*a1, g2*a2, g3*a3);
  }
  if (tid < MT*KK) {
    const int m = tid >> 2, k = tid & 3;
    const float4* row = (const float4*)(alpha + (size_t)k*MT*MT + m*MT);
    float s = 0.f;
    #pragma unroll
    for (int j = 0; j < MT/4; ++j) { float4 v = row[j]; s += (v.x+v.y)+(v.z+v.w); }
    ((float*)asumS)[(m<<2)+k] = s;
  }
  __syncthreads();

  const float T = parse_T(Tp);
  const int s0w = (int)blockIdx.x * 8 * B;
  const int b  = (int)blockIdx.x*8 + wv;
  const int s0 = b*B, e0 = min(N, s0+B);
  float4 q = make_float4(0.f,0.f,0.f,0.f);
  float comp = 0.f;
  const int nch = (B + MAXB - 1) / MAXB;              // 1 for N<=200704

  for (int ch = 0; ch < nch; ++ch) {
    const int c0 = ch*MAXB;
    const int cb = min(B - c0, MAXB);
    const int tot = 8*cb;
    // ---- parallel fill: d4/mi tiles + compensator ----
    for (int jj = tid; jj < tot; jj += 512) {
      int w = jj / cb, lo = jj - w*cb;
      int i = s0w + w*B + c0 + lo;
      if (i < N) {
        float ti = t[i];
        float tp = (i > 0) ? t[i-1] : ti;
        float dt = ti - tp;
        d4t[jj] = make_float4(__expf(-g0*dt), __expf(-g1*dt),
                              __expf(-g2*dt), __expf(-g3*dt));
        int m = mi[i];
        miL[jj] = (unsigned char)m;
        float y = T - ti;
        float4 as = asumS[m];
        comp = fmaf(as.x, 1.f-__expf(-g0*y), comp);
        comp = fmaf(as.y, 1.f-__expf(-g1*y), comp);
        comp = fmaf(as.z, 1.f-__expf(-g2*y), comp);
        comp = fmaf(as.w, 1.f-__expf(-g3*y), comp);
      }
    }
    __syncthreads();
    // ---- wave-per-block serial scan (LDS only; no transcendentals) ----
    const int iend = min(cb, e0 - s0 - c0);
    int j = wv*cb;
    #pragma unroll 4
    for (int ii = 0; ii < iend; ++ii, ++j) {
      float4 d = d4t[j];                              // wave-uniform broadcast
      int m = miL[j];                                 // wave-uniform
      float4 a = AT4[(m<<6) + lane];                  // 1KB/wave, conflict-free
      float s = q.x*d.x; s=fmaf(q.y,d.y,s); s=fmaf(q.z,d.z,s); s=fmaf(q.w,d.w,s);
      if (lane == m) sL[j] = s;                       // local intensity at event
      q = f4fma(q, d, a);
    }
    __syncthreads();
    // ---- copy s_loc to global (coalesced) ----
    for (int jj = tid; jj < tot; jj += 512) {
      int w = jj / cb, lo = jj - w*cb;
      int i = s0w + w*B + c0 + lo;
      if (i < N) slG[i] = sL[jj];
    }
    __syncthreads();
  }

  comp = wredf(comp);
  if (lane == 0) red[wv] = comp;

  float4 df = make_float4(1.f,1.f,1.f,1.f);
  if (lane == 0) {
    int last  = max(e0-1, 0);
    int plast = min(max(s0-1, 0), N-1);
    float dtb = t[last] - t[plast];
    df = make_float4(__expf(-g0*dtb),__expf(-g1*dtb),
                     __expf(-g2*dtb),__expf(-g3*dtb));
  }
  cw[wv*64 + lane] = q;
  if (lane == 0) cwd[wv] = df;
  __syncthreads();

  float4 c  = make_float4(0.f,0.f,0.f,0.f);
  float4 dp = make_float4(1.f,1.f,1.f,1.f);
  float4 Cl = c, Dc = dp;
  #pragma unroll
  for (int jo = 0; jo < 8; ++jo) {
    if (jo == wv) { Cl = c; Dc = dp; }
    float4 d = cwd[jo];
    float4 P = cw[jo*64 + lane];
    c  = f4fma(c, d, P);
    dp = f4mul(dp, d);
  }
  Cl8[(size_t)b*64 + lane] = Cl;
  if (lane == 0) Dc8[b] = Dc;
  if (wv == 0) {
    Ag[(size_t)blockIdx.x*64 + lane] = c;
    if (lane == 0) gdec[blockIdx.x] = dp;
    if (lane == 0) {
      float cc = 0.f;
      #pragma unroll
      for (int jr = 0; jr < 8; ++jr) cc += red[jr];
      compP[blockIdx.x] = cc;
    }
  }
}

// ---------- K2: supergroup aggregates — batched prefetch (R11-proven) ----------
__global__ __launch_bounds__(64) void k_scan2(
    const float4* __restrict__ Ag, const float4* __restrict__ gdec,
    float4* __restrict__ SgG, float4* __restrict__ sdecG)
{
  const int lane = threadIdx.x;
  const int s = blockIdx.x;
  float4 c  = make_float4(0.f,0.f,0.f,0.f);
  float4 dp = make_float4(1.f,1.f,1.f,1.f);
  const int o0 = s*32;
  #pragma unroll
  for (int bb = 0; bb < 4; ++bb) {
    float4 av[8], gv[8];
    #pragma unroll
    for (int j = 0; j < 8; ++j) {               // 16 independent loads in flight
      const int o = o0 + bb*8 + j;
      av[j] = Ag[(size_t)o*64 + lane];
      gv[j] = gdec[o];
    }
    #pragma unroll
    for (int j = 0; j < 8; ++j) {               // register-only compose
      c  = f4fma(c, gv[j], av[j]);
      dp = f4mul(dp, gv[j]);
    }
  }
  SgG[(size_t)s*64 + lane] = c;
  if (lane == 0) sdecG[s] = dp;
}

// ---------- K3: per-event intensity + single fence-free atomic final ----------
__global__ __launch_bounds__(512, 4) void k_lam(
    const float* __restrict__ t, const int* __restrict__ mi,
    const float* __restrict__ gamma, const float* __restrict__ mu,
    const int* __restrict__ Tp,
    const float* __restrict__ slG,
    const float4* __restrict__ Cl8, const float4* __restrict__ Dc8,
    const float4* __restrict__ Ag, const float4* __restrict__ gdec,
    const float4* __restrict__ SgG, const float4* __restrict__ sdecG,
    const float* __restrict__ compP,
    float* __restrict__ out, int N, int B)
{
  __shared__ float4 TopL[64];
  __shared__ float4 gpL[64];
  __shared__ float4 gdLs;
  __shared__ float4 C_L[8*64];         // per-(block,m) composed carry, 8 KB
  __shared__ float red[8];
  const int tid = threadIdx.x, lane = tid & 63, wv = tid >> 6;
  const int oct = blockIdx.x;
  const int sup = oct >> 5;
  const int BPW = 8*B;
  const int i = oct*BPW + tid;
  const float g0=gamma[0], g1=gamma[1], g2=gamma[2], g3=gamma[3];

  // ---- hoisted per-event loads (fly during the fold prologue) ----
  int   m = 0;
  float4 cd; float sl = 0.f, muv = 0.f;
  const bool valid = (tid < BPW) && (i < N);
  if (valid) {
    m  = mi[i];
    sl = slG[i];
    muv = mu[m];
    int bl = tid / B;
    float ti = t[i];
    int refi = (oct*8 + bl)*B - 1;
    float tr = (refi >= 0) ? t[refi] : t[0];
    float x = ti - tr;
    cd = make_float4(__expf(-g0*x), __expf(-g1*x), __expf(-g2*x), __expf(-g3*x));
  }

  float muS = 0.f;                      // only meaningful on oct 0, wave 0
  if (wv == 0) {                        // Top: carry into this supergroup (<=15 steps)
    if (oct == 0) muS = wredf(mu[lane]);
    float4 tc = make_float4(0.f,0.f,0.f,0.f);
    int s = 0;
    for (; s + 4 <= sup; s += 4) {
      float4 av[4], gv[4];
      #pragma unroll
      for (int j = 0; j < 4; ++j) {
        av[j] = SgG[(size_t)(s+j)*64 + lane];
        gv[j] = sdecG[s+j];
      }
      #pragma unroll
      for (int j = 0; j < 4; ++j) tc = f4fma(tc, gv[j], av[j]);
    }
    for (; s < sup; ++s) tc = f4fma(tc, sdecG[s], SgG[(size_t)s*64 + lane]);
    TopL[lane] = tc;
  } else if (wv == 1) {                 // gp/gd: carry into octet within super (<=31)
    float4 gp = make_float4(0.f,0.f,0.f,0.f);
    float4 gd = make_float4(1.f,1.f,1.f,1.f);
    int o = sup << 5;
    for (; o + 4 <= oct; o += 4) {
      float4 av[4], gv[4];
      #pragma unroll
      for (int j = 0; j < 4; ++j) {
        av[j] = Ag[(size_t)(o+j)*64 + lane];
        gv[j] = gdec[o+j];
      }
      #pragma unroll
      for (int j = 0; j < 4; ++j) {
        gp = f4fma(gp, gv[j], av[j]);
        gd = f4mul(gd, gv[j]);
      }
    }
    for (; o < oct; ++o) {
      gp = f4fma(gp, gdec[o], Ag[(size_t)o*64 + lane]);
      gd = f4mul(gd, gdec[o]);
    }
    gpL[lane] = gp;
    if (lane == 0) gdLs = gd;
  }
  __syncthreads();

  // ---- build per-(block,m) carry table: 512 threads = 8 blocks x 64 m, coalesced ----
  {
    const int bl2 = wv;                               // block index within octet
    const int m2  = lane;                             // type index
    const int b2  = oct*8 + bl2;
    float4 coct = f4fma(gdLs, TopL[m2], gpL[m2]);     // carry into octet, type m2
    C_L[(bl2<<6) + m2] = f4fma(Dc8[b2], coct, Cl8[(size_t)b2*64 + m2]);
  }
  __syncthreads();

  // ---- per-event intensity ----
  float v = 0.f;
  if (valid) {
    int bl = tid / B;
    float4 C = C_L[(bl<<6) + m];
    float lam = muv + sl + (C.x*cd.x + C.y*cd.y + C.z*cd.z + C.w*cd.w);
    v = __log2f(lam);
  }
  v = wredf(v);
  if (lane == 0) red[wv] = v;
  __syncthreads();
  if (tid == 0) {                       // one bare atomicAdd per WG; no fences
    float s = 0.f;
    #pragma unroll
    for (int j = 0; j < 8; ++j) s += red[j];
    const float invN = 1.f / (float)N;
    float term = (compP[oct] - 0.69314718055994531f * s) * invN;
    if (oct == 0) term = fmaf(parse_T(Tp) * muS, invN, term);
    atomicAdd(out, term);
  }
}

extern "C" void kernel_launch(void* const* d_in, const int* in_sizes, int n_in,
                              void* d_out, int out_size, void* d_ws, size_t ws_size,
                              hipStream_t stream)
{
  const float* mu    = (const float*)d_in[0];
  const float* alpha = (const float*)d_in[1];   // (K, M, M)
  const float* gamma = (const float*)d_in[2];   // (K,)
  const float* t     = (const float*)d_in[3];   // (N,)
  const int*   mi    = (const int*)d_in[4];     // (N,) int32
  const int*   Tp    = (const int*)d_in[5];     // scalar
  const int N = in_sizes[3];
  const int B   = (N + NBK - 1) / NBK;          // 49 at N=200k
  const int NOG = NBK / 8;                      // 512 WGs / octets
  float* outp = (float*)d_out;

  float* p = (float*)d_ws;
  float*  slG   = p;          p += ((size_t)N + 3) & ~(size_t)3;
  float4* Cl8   = (float4*)p; p += (size_t)NBK*256;
  float4* Dc8   = (float4*)p; p += (size_t)NBK*4;
  float4* Ag    = (float4*)p; p += (size_t)NOG*256;
  float4* gdec  = (float4*)p; p += (size_t)NOG*4;
  float4* SgG   = (float4*)p; p += (size_t)16*256;
  float4* sdecG = (float4*)p; p += (size_t)16*4;
  float*  compP = p;          p += NOG;

  k_phase1<<<NOG, 512, 0, stream>>>(t, mi, alpha, gamma, Tp, slG,
                                    Cl8, Dc8, Ag, gdec, compP, outp, N, B);
  k_scan2 <<<16,  64,  0, stream>>>(Ag, gdec, SgG, sdecG);
  k_lam   <<<NOG, 512, 0, stream>>>(t, mi, gamma, mu, Tp, slG, Cl8, Dc8,
                                    Ag, gdec, SgG, sdecG, compP, outp, N, B);
}

// Round 16
// 32.540 us; speedup vs baseline: 1.0379x; 1.0379x over previous
//
#include <hip/hip_runtime.h>

#define MT 64     // number of event types M
#define KK 4      // number of kernels K
#define NBK 4096  // scan blocks (512 WGs x 8 waves)
#define MAXB 49   // events/block per LDS chunk (N <= 200704 in one chunk; larger N loops)

// ---------- helpers ----------
__device__ __forceinline__ float wredf(float v) {
  #pragma unroll
  for (int off = 32; off > 0; off >>= 1) v += __shfl_xor(v, off, 64);
  return v;
}
__device__ __forceinline__ double wredd(double v) {
  #pragma unroll
  for (int off = 32; off > 0; off >>= 1) v += __shfl_xor(v, off, 64);
  return v;
}
__device__ __forceinline__ float4 f4fma(float4 a, float4 b, float4 c) { // a*b+c
  return make_float4(fmaf(a.x,b.x,c.x), fmaf(a.y,b.y,c.y),
                     fmaf(a.z,b.z,c.z), fmaf(a.w,b.w,c.w));
}
__device__ __forceinline__ float4 f4mul(float4 a, float4 b) {
  return make_float4(a.x*b.x, a.y*b.y, a.z*b.z, a.w*b.w);
}
__device__ __forceinline__ float parse_T(const int* Tp) {
  int v = *Tp;
  if (v >= 1 && v <= 1000000000) return (float)v;
  return __int_as_float(v);
}

// ---------- K1: single serial pass (R11/R14-proven) ----------
__global__ __launch_bounds__(512, 4) void k_phase1(
    const float* __restrict__ t, const int* __restrict__ mi,
    const float* __restrict__ alpha, const float* __restrict__ gamma,
    const int* __restrict__ Tp,
    float* __restrict__ slG,
    float4* __restrict__ Cl8, float4* __restrict__ Dc8,
    float4* __restrict__ Ag, float4* __restrict__ gdec,
    float* __restrict__ compP, int N, int B)
{
  __shared__ float4 AT4[MT*MT];                       // 64 KB
  __shared__ __align__(16) unsigned char pool[8320];  // d4t+miL (serial) / cw+cwd (scan)
  __shared__ float sL[8*MAXB];                        // per-event local intensity
  __shared__ float4 asumS[MT];
  __shared__ float red[8];
  float4*        d4t = (float4*)pool;                 // [8*MAXB]
  unsigned char* miL = pool + 8*MAXB*16;              // [8*MAXB]
  float4*        cw  = (float4*)pool;                 // [512] post-serial overlay
  float4*        cwd = (float4*)(pool + 8192);        // [8]

  const int tid = threadIdx.x, lane = tid & 63, wv = tid >> 6;
  const float g0=gamma[0], g1=gamma[1], g2=gamma[2], g3=gamma[3];

  #pragma unroll
  for (int idx = tid; idx < MT*MT; idx += 512) {
    float a0=alpha[idx],         a1=alpha[MT*MT+idx];
    float a2=alpha[2*MT*MT+idx], a3=alpha[3*MT*MT+idx];
    AT4[idx] = make_float4(g0*a0, g1*a1, g2*a2, g3*a3);
  }
  if (tid < MT*KK) {
    const int m = tid >> 2, k = tid & 3;
    const float4* row = (const float4*)(alpha + (size_t)k*MT*MT + m*MT);
    float s = 0.f;
    #pragma unroll
    for (int j = 0; j < MT/4; ++j) { float4 v = row[j]; s += (v.x+v.y)+(v.z+v.w); }
    ((float*)asumS)[(m<<2)+k] = s;
  }
  __syncthreads();

  const float T = parse_T(Tp);
  const int s0w = (int)blockIdx.x * 8 * B;
  const int b  = (int)blockIdx.x*8 + wv;
  const int s0 = b*B, e0 = min(N, s0+B);
  float4 q = make_float4(0.f,0.f,0.f,0.f);
  float comp = 0.f;
  const int nch = (B + MAXB - 1) / MAXB;              // 1 for N<=200704

  for (int ch = 0; ch < nch; ++ch) {
    const int c0 = ch*MAXB;
    const int cb = min(B - c0, MAXB);
    const int tot = 8*cb;
    // ---- parallel fill: d4/mi tiles + compensator ----
    for (int jj = tid; jj < tot; jj += 512) {
      int w = jj / cb, lo = jj - w*cb;
      int i = s0w + w*B + c0 + lo;
      if (i < N) {
        float ti = t[i];
        float tp = (i > 0) ? t[i-1] : ti;
        float dt = ti - tp;
        d4t[jj] = make_float4(__expf(-g0*dt), __expf(-g1*dt),
                              __expf(-g2*dt), __expf(-g3*dt));
        int m = mi[i];
        miL[jj] = (unsigned char)m;
        float y = T - ti;
        float4 as = asumS[m];
        comp = fmaf(as.x, 1.f-__expf(-g0*y), comp);
        comp = fmaf(as.y, 1.f-__expf(-g1*y), comp);
        comp = fmaf(as.z, 1.f-__expf(-g2*y), comp);
        comp = fmaf(as.w, 1.f-__expf(-g3*y), comp);
      }
    }
    __syncthreads();
    // ---- wave-per-block serial scan (LDS only; no transcendentals) ----
    const int iend = min(cb, e0 - s0 - c0);
    int j = wv*cb;
    #pragma unroll 4
    for (int ii = 0; ii < iend; ++ii, ++j) {
      float4 d = d4t[j];                              // wave-uniform broadcast
      int m = miL[j];                                 // wave-uniform
      float4 a = AT4[(m<<6) + lane];                  // 1KB/wave, conflict-free
      float s = q.x*d.x; s=fmaf(q.y,d.y,s); s=fmaf(q.z,d.z,s); s=fmaf(q.w,d.w,s);
      if (lane == m) sL[j] = s;                       // local intensity at event
      q = f4fma(q, d, a);
    }
    __syncthreads();
    // ---- copy s_loc to global (coalesced) ----
    for (int jj = tid; jj < tot; jj += 512) {
      int w = jj / cb, lo = jj - w*cb;
      int i = s0w + w*B + c0 + lo;
      if (i < N) slG[i] = sL[jj];
    }
    __syncthreads();
  }

  comp = wredf(comp);
  if (lane == 0) red[wv] = comp;

  float4 df = make_float4(1.f,1.f,1.f,1.f);
  if (lane == 0) {
    int last  = max(e0-1, 0);
    int plast = min(max(s0-1, 0), N-1);
    float dtb = t[last] - t[plast];
    df = make_float4(__expf(-g0*dtb),__expf(-g1*dtb),
                     __expf(-g2*dtb),__expf(-g3*dtb));
  }
  cw[wv*64 + lane] = q;
  if (lane == 0) cwd[wv] = df;
  __syncthreads();

  float4 c  = make_float4(0.f,0.f,0.f,0.f);
  float4 dp = make_float4(1.f,1.f,1.f,1.f);
  float4 Cl = c, Dc = dp;
  #pragma unroll
  for (int jo = 0; jo < 8; ++jo) {
    if (jo == wv) { Cl = c; Dc = dp; }
    float4 d = cwd[jo];
    float4 P = cw[jo*64 + lane];
    c  = f4fma(c, d, P);
    dp = f4mul(dp, d);
  }
  Cl8[(size_t)b*64 + lane] = Cl;
  if (lane == 0) Dc8[b] = Dc;
  if (wv == 0) {
    Ag[(size_t)blockIdx.x*64 + lane] = c;
    if (lane == 0) gdec[blockIdx.x] = dp;
    if (lane == 0) {
      float cc = 0.f;
      #pragma unroll
      for (int jr = 0; jr < 8; ++jr) cc += red[jr];
      compP[blockIdx.x] = cc;
    }
  }
}

// ---------- K2: supergroup aggregates — batched prefetch (R11-proven) ----------
__global__ __launch_bounds__(64) void k_scan2(
    const float4* __restrict__ Ag, const float4* __restrict__ gdec,
    float4* __restrict__ SgG, float4* __restrict__ sdecG)
{
  const int lane = threadIdx.x;
  const int s = blockIdx.x;
  float4 c  = make_float4(0.f,0.f,0.f,0.f);
  float4 dp = make_float4(1.f,1.f,1.f,1.f);
  const int o0 = s*32;
  #pragma unroll
  for (int bb = 0; bb < 4; ++bb) {
    float4 av[8], gv[8];
    #pragma unroll
    for (int j = 0; j < 8; ++j) {               // 16 independent loads in flight
      const int o = o0 + bb*8 + j;
      av[j] = Ag[(size_t)o*64 + lane];
      gv[j] = gdec[o];
    }
    #pragma unroll
    for (int j = 0; j < 8; ++j) {               // register-only compose
      c  = f4fma(c, gv[j], av[j]);
      dp = f4mul(dp, gv[j]);
    }
  }
  SgG[(size_t)s*64 + lane] = c;
  if (lane == 0) sdecG[s] = dp;
}

// ---------- K3: per-event intensity; cd recomputed from t; C_L carry table in LDS ----------
__global__ __launch_bounds__(512, 4) void k_lam(
    const float* __restrict__ t, const int* __restrict__ mi,
    const float* __restrict__ gamma, const float* __restrict__ mu,
    const float* __restrict__ slG,
    const float4* __restrict__ Cl8, const float4* __restrict__ Dc8,
    const float4* __restrict__ Ag, const float4* __restrict__ gdec,
    const float4* __restrict__ SgG, const float4* __restrict__ sdecG,
    float* __restrict__ npt, int N, int B)
{
  __shared__ float4 TopL[64];
  __shared__ float4 gpL[64];
  __shared__ float4 gdLs;
  __shared__ float4 C_L[8*64];         // per-(block,m) composed carry, 8 KB
  __shared__ float red[8];
  const int tid = threadIdx.x, lane = tid & 63, wv = tid >> 6;
  const int oct = blockIdx.x;
  const int sup = oct >> 5;
  const int BPW = 8*B;
  const int i = oct*BPW + tid;
  const float g0=gamma[0], g1=gamma[1], g2=gamma[2], g3=gamma[3];

  // ---- hoisted per-event loads (fly during the fold prologue) ----
  int   m = 0;
  float4 cd; float sl = 0.f, muv = 0.f;
  const bool valid = (tid < BPW) && (i < N);
  if (valid) {
    m  = mi[i];
    sl = slG[i];
    muv = mu[m];
    int bl = tid / B;
    float ti = t[i];
    int refi = (oct*8 + bl)*B - 1;
    float tr = (refi >= 0) ? t[refi] : t[0];
    float x = ti - tr;
    cd = make_float4(__expf(-g0*x), __expf(-g1*x), __expf(-g2*x), __expf(-g3*x));
  }

  if (wv == 0) {                        // Top: carry into this supergroup (<=15 steps)
    float4 tc = make_float4(0.f,0.f,0.f,0.f);
    int s = 0;
    for (; s + 4 <= sup; s += 4) {
      float4 av[4], gv[4];
      #pragma unroll
      for (int j = 0; j < 4; ++j) {
        av[j] = SgG[(size_t)(s+j)*64 + lane];
        gv[j] = sdecG[s+j];
      }
      #pragma unroll
      for (int j = 0; j < 4; ++j) tc = f4fma(tc, gv[j], av[j]);
    }
    for (; s < sup; ++s) tc = f4fma(tc, sdecG[s], SgG[(size_t)s*64 + lane]);
    TopL[lane] = tc;
  } else if (wv == 1) {                 // gp/gd: carry into octet within super (<=31)
    float4 gp = make_float4(0.f,0.f,0.f,0.f);
    float4 gd = make_float4(1.f,1.f,1.f,1.f);
    int o = sup << 5;
    for (; o + 4 <= oct; o += 4) {
      float4 av[4], gv[4];
      #pragma unroll
      for (int j = 0; j < 4; ++j) {
        av[j] = Ag[(size_t)(o+j)*64 + lane];
        gv[j] = gdec[o+j];
      }
      #pragma unroll
      for (int j = 0; j < 4; ++j) {
        gp = f4fma(gp, gv[j], av[j]);
        gd = f4mul(gd, gv[j]);
      }
    }
    for (; o < oct; ++o) {
      gp = f4fma(gp, gdec[o], Ag[(size_t)o*64 + lane]);
      gd = f4mul(gd, gdec[o]);
    }
    gpL[lane] = gp;
    if (lane == 0) gdLs = gd;
  }
  __syncthreads();

  // ---- build per-(block,m) carry table: 512 threads = 8 blocks x 64 m, coalesced ----
  {
    const int bl2 = wv;                               // block index within octet
    const int m2  = lane;                             // type index
    const int b2  = oct*8 + bl2;
    float4 coct = f4fma(gdLs, TopL[m2], gpL[m2]);     // carry into octet, type m2
    C_L[(bl2<<6) + m2] = f4fma(Dc8[b2], coct, Cl8[(size_t)b2*64 + m2]);
  }
  __syncthreads();

  // ---- per-event intensity ----
  float v = 0.f;
  if (valid) {
    int bl = tid / B;
    float4 C = C_L[(bl<<6) + m];
    float lam = muv + sl + (C.x*cd.x + C.y*cd.y + C.z*cd.z + C.w*cd.w);
    v = __log2f(lam);
  }
  v = wredf(v);
  if (lane == 0) red[wv] = v;
  __syncthreads();
  if (tid == 0) {
    float s = 0.f;
    #pragma unroll
    for (int j = 0; j < 8; ++j) s += red[j];
    npt[oct] = s;
  }
}

// ---------- K4: deterministic final reduction ----------
__global__ __launch_bounds__(512) void k_final(
    const float* __restrict__ mu, const int* __restrict__ Tp,
    const float* __restrict__ compP, int nc,
    const float* __restrict__ npt, int nn,
    float* __restrict__ out, int N)
{
  const int tid = threadIdx.x;
  double sc = 0.0, sn = 0.0;
  for (int i = tid; i < nc; i += 512) sc += (double)compP[i];
  for (int i = tid; i < nn; i += 512) sn += (double)npt[i];
  double sm = (tid < MT) ? (double)mu[tid] : 0.0;
  sc = wredd(sc); sn = wredd(sn); sm = wredd(sm);
  __shared__ double s3[3][8];
  const int wv = tid >> 6, lane = tid & 63;
  if (lane == 0) { s3[0][wv]=sc; s3[1][wv]=sn; s3[2][wv]=sm; }
  __syncthreads();
  if (tid == 0) {
    double C=0.0, L=0.0, Mm=0.0;
    #pragma unroll
    for (int j = 0; j < 8; ++j) { C+=s3[0][j]; L+=s3[1][j]; Mm+=s3[2][j]; }
    L *= 0.6931471805599453;             // acc was log2
    double T = (double)parse_T(Tp);
    out[0] = (float)((C + T*Mm - L) / (double)N);
  }
}

extern "C" void kernel_launch(void* const* d_in, const int* in_sizes, int n_in,
                              void* d_out, int out_size, void* d_ws, size_t ws_size,
                              hipStream_t stream)
{
  const float* mu    = (const float*)d_in[0];
  const float* alpha = (const float*)d_in[1];   // (K, M, M)
  const float* gamma = (const float*)d_in[2];   // (K,)
  const float* t     = (const float*)d_in[3];   // (N,)
  const int*   mi    = (const int*)d_in[4];     // (N,) int32
  const int*   Tp    = (const int*)d_in[5];     // scalar
  const int N = in_sizes[3];
  const int B   = (N + NBK - 1) / NBK;          // 49 at N=200k
  const int NOG = NBK / 8;                      // 512 WGs / octets

  float* p = (float*)d_ws;
  float*  slG   = p;          p += ((size_t)N + 3) & ~(size_t)3;
  float4* Cl8   = (float4*)p; p += (size_t)NBK*256;
  float4* Dc8   = (float4*)p; p += (size_t)NBK*4;
  float4* Ag    = (float4*)p; p += (size_t)NOG*256;
  float4* gdec  = (float4*)p; p += (size_t)NOG*4;
  float4* SgG   = (float4*)p; p += (size_t)16*256;
  float4* sdecG = (float4*)p; p += (size_t)16*4;
  float*  compP = p;          p += NOG;
  float*  npt   = p;          p += NOG;

  k_phase1<<<NOG, 512, 0, stream>>>(t, mi, alpha, gamma, Tp, slG,
                                    Cl8, Dc8, Ag, gdec, compP, N, B);
  k_scan2 <<<16,  64,  0, stream>>>(Ag, gdec, SgG, sdecG);
  k_lam   <<<NOG, 512, 0, stream>>>(t, mi, gamma, mu, slG, Cl8, Dc8, Ag, gdec,
                                    SgG, sdecG, npt, N, B);
  k_final <<<1,   512, 0, stream>>>(mu, Tp, compP, NOG, npt, NOG,
                                    (float*)d_out, N);
}